// Round 4
// baseline (2633.106 us; speedup 1.0000x reference)
//
#include <hip/hip_runtime.h>
#include <hip/hip_bf16.h>

// ---------------------------------------------------------------------------
// Mamba2 mixer forward on MI355X (gfx950).
// HID=2048 DSTATE=128 K=4 DIN=4096 HDIM=64 NH=64 CHUNK=256, B=2 L=4096
//
// Precision plan (absmax budget 0.108, ref fp32):
//   - z, x paths: bf16 (linear, small amplification)
//   - B, C, dt: FULL FP32 (cols 8192..8512 of zxbcdt) — CB=sum_128 C*B and
//     exp(cumsum(dt*A)) amplify bf16 noise ~25 ulps; fp32 end-to-end here.
//   - CB, Lmat, chunk states, scan: fp32.
//
// Workspace (~166 MiB):
//   x_pre [8192,4096] bf16 (67.1MB) -- GEMM1 x out; reused as cs/prev fp32
//   xq    [8192,4096] bf16 (67.1MB) -- conv x out; overwritten by Y, then norm
//   bcr   [8192,256]  f32  (8.4MB)  -- B,C pre-conv (fp32 GEMM)
//   bcc   [8192,256]  f32  (8.4MB)  -- B,C post conv+SiLU
//   dt_f  [8192,64]   f32  (2.1MB)
//   acs_f [2,16,64,256] f32 (2.1MB), cd_f [2,64,16] f32
//   cbt_f [2,16,256,256] f32 (8.4MB)
// z (bf16 [8192,4096], 67.1MB) lives in d_out until GEMM2 rewrites it.
// ---------------------------------------------------------------------------

typedef __bf16 v8bf __attribute__((ext_vector_type(8)));
typedef float  v4f  __attribute__((ext_vector_type(4)));

#define LL long long

__device__ inline v8bf load8(const __bf16* p) { return *(const v8bf*)p; }
__device__ inline v8bf load8(const float* p) {
    v4f a = *(const v4f*)p, b = *(const v4f*)(p + 4);
    v8bf r;
#pragma unroll
    for (int i = 0; i < 4; ++i) { r[i] = (__bf16)a[i]; r[i + 4] = (__bf16)b[i]; }
    return r;
}

// ---------------- bf16 MFMA GEMM:  C[M,N] = A[M,K] * B[N,K]^T ----------------
// 128x128 block tile, 4 waves, each wave 64x64 (4x4 of 16x16x32 MFMA).
// MODE 1: split epilogue (col<4096 -> z bf16, else -> x bf16)
// MODE 2: fp32 C
template <typename TA, typename TB, int MODE>
__global__ __launch_bounds__(256) void gemm_bt(
    const TA* __restrict__ A, const TB* __restrict__ B, int K, int lda, int ldb,
    __bf16* __restrict__ z_out, __bf16* __restrict__ x_out,
    float* __restrict__ outf, int ldc)
{
    __shared__ __align__(16) __bf16 As[128][40];
    __shared__ __align__(16) __bf16 Bs[128][40];
    const int tid  = threadIdx.x;
    const int lane = tid & 63;
    const int wave = tid >> 6;
    const int wm = (wave & 1) * 64, wn = (wave >> 1) * 64;
    const int m0 = blockIdx.y * 128, n0 = blockIdx.x * 128;
    const int lrow = lane & 15, quad = lane >> 4;
    v4f acc[4][4] = {};

    for (int k0 = 0; k0 < K; k0 += 32) {
#pragma unroll
        for (int i = 0; i < 2; ++i) {
            int e = tid + i * 256;            // 0..511
            int row = e >> 2, c8 = (e & 3) << 3;
            *(v8bf*)&As[row][c8] = load8(&A[(LL)(m0 + row) * lda + k0 + c8]);
            *(v8bf*)&Bs[row][c8] = load8(&B[(LL)(n0 + row) * ldb + k0 + c8]);
        }
        __syncthreads();
        v8bf af[4], bfr[4];
#pragma unroll
        for (int i = 0; i < 4; ++i) af[i]  = *(const v8bf*)&As[wm + i * 16 + lrow][quad * 8];
#pragma unroll
        for (int j = 0; j < 4; ++j) bfr[j] = *(const v8bf*)&Bs[wn + j * 16 + lrow][quad * 8];
#pragma unroll
        for (int i = 0; i < 4; ++i)
#pragma unroll
            for (int j = 0; j < 4; ++j)
                acc[i][j] = __builtin_amdgcn_mfma_f32_16x16x32_bf16(af[i], bfr[j], acc[i][j], 0, 0, 0);
        __syncthreads();
    }
#pragma unroll
    for (int i = 0; i < 4; ++i)
#pragma unroll
        for (int j = 0; j < 4; ++j)
#pragma unroll
            for (int r = 0; r < 4; ++r) {
                int row = m0 + wm + i * 16 + quad * 4 + r;
                int col = n0 + wn + j * 16 + lrow;
                float v = acc[i][j][r];
                if constexpr (MODE == 1) {
                    if (col < 4096) z_out[(LL)row * 4096 + col] = (__bf16)v;
                    else            x_out[(LL)row * 4096 + (col - 4096)] = (__bf16)v;
                } else {
                    outf[(LL)row * ldc + col] = v;
                }
            }
}

// ---------------- fp32 GEMM for B/C/dt columns (zxbcdt cols 8192..8512) ------
// grid (128 rowblocks, 5 colgroups); block computes 64 rows x 64 cols, K=2048.
// colgroup 0..3 -> B,C raw (bcr); colgroup 4 -> dt = softplus(. + dtbi)
__global__ __launch_bounds__(256) void f32_gemm_kernel(
    const float* __restrict__ hs, const float* __restrict__ w1,
    const float* __restrict__ dtbi, float* __restrict__ bcr,
    float* __restrict__ dt)
{
    const int row0 = blockIdx.x * 64;
    const int cg = blockIdx.y;               // 0..4
    const int wrow0 = 8192 + cg * 64;        // w1 row block
    const int t = threadIdx.x;
    const int col = t & 63, rg = t >> 6;     // each thread: 16 rows x 1 col
    __shared__ __align__(16) float As[64][68];   // As[kk][row]
    __shared__ __align__(16) float Ws[64][68];   // Ws[kk][wcol]
    float acc[16] = {};
    for (int k0 = 0; k0 < 2048; k0 += 64) {
#pragma unroll
        for (int i = 0; i < 16; ++i) {
            int e = t + i * 256; int kk = e & 63, row = e >> 6;
            As[kk][row] = hs[(LL)(row0 + row) * 2048 + k0 + kk];
            Ws[kk][row] = w1[(LL)(wrow0 + row) * 2048 + k0 + kk];
        }
        __syncthreads();
        for (int kk = 0; kk < 64; ++kk) {
            float w = Ws[kk][col];
#pragma unroll
            for (int q = 0; q < 4; ++q) {
                v4f a = *(const v4f*)&As[kk][rg * 16 + q * 4];
#pragma unroll
                for (int j = 0; j < 4; ++j) acc[q * 4 + j] += a[j] * w;
            }
        }
        __syncthreads();
    }
    if (cg < 4) {
#pragma unroll
        for (int i = 0; i < 16; ++i) {
            int row = row0 + rg * 16 + i;
            bcr[(LL)row * 256 + cg * 64 + col] = acc[i];
        }
    } else {
        float bias = dtbi[col];
#pragma unroll
        for (int i = 0; i < 16; ++i) {
            int row = row0 + rg * 16 + i;
            float x = acc[i] + bias;
            dt[row * 64 + col] = (x > 20.f) ? x : log1pf(__expf(x));
        }
    }
}

// ---------------- causal conv1d (K=4) + SiLU, x channels (bf16) --------------
__global__ __launch_bounds__(256) void conv_x_kernel(
    const __bf16* __restrict__ xp, const float* __restrict__ cw,
    const float* __restrict__ cbias, __bf16* __restrict__ xq)
{
    int ch = blockIdx.x * 256 + threadIdx.x;  // 0..4095
    int l = blockIdx.y, b = blockIdx.z;
    float acc = cbias[ch];
#pragma unroll
    for (int i = 0; i < 4; ++i) {
        int ls = l - 3 + i;
        if (ls >= 0)
            acc += (float)xp[((LL)b * 4096 + ls) * 4096 + ch] * cw[ch * 4 + i];
    }
    acc = acc / (1.f + __expf(-acc));
    xq[((LL)b * 4096 + l) * 4096 + ch] = (__bf16)acc;
}

// ---------------- causal conv1d (K=4) + SiLU, B/C channels (fp32) ------------
__global__ __launch_bounds__(256) void conv_bc_kernel(
    const float* __restrict__ bcr, const float* __restrict__ cw,
    const float* __restrict__ cbias, float* __restrict__ bcc)
{
    int ch = threadIdx.x;                     // 0..255
    int l = blockIdx.y, b = blockIdx.z;
    float acc = cbias[4096 + ch];
#pragma unroll
    for (int i = 0; i < 4; ++i) {
        int ls = l - 3 + i;
        if (ls >= 0)
            acc += bcr[((LL)b * 4096 + ls) * 256 + ch] * cw[(4096 + ch) * 4 + i];
    }
    acc = acc / (1.f + __expf(-acc));
    bcc[((LL)b * 4096 + l) * 256 + ch] = acc;
}

// ---------------- per-chunk inclusive cumsum of dA = dt*A --------------------
__global__ __launch_bounds__(256) void cumsum_kernel(
    const float* __restrict__ dt, const float* __restrict__ alog,
    float* __restrict__ acs, float* __restrict__ cdec)
{
    int h = blockIdx.x, c = blockIdx.y, b = blockIdx.z;
    int s = threadIdx.x;
    __shared__ float buf[256];
    float Av = -expf(alog[h]);
    int bl = b * 4096 + c * 256 + s;
    buf[s] = dt[bl * 64 + h] * Av;
    __syncthreads();
    for (int off = 1; off < 256; off <<= 1) {
        float v = (s >= off) ? buf[s - off] : 0.f;
        __syncthreads();
        buf[s] += v;
        __syncthreads();
    }
    int abase = (((b * 16) + c) * 64 + h) * 256;
    acs[abase + s] = buf[s];
    if (s == 255) cdec[(b * 64 + h) * 16 + c] = expf(buf[s]);
}

// ---------------- chunk states: cs[b,c,h,p,n] = sum_s B[s,n]*dec[s]*x[s,p]*dt[s]
__global__ __launch_bounds__(256) void chunk_state_kernel(
    const __bf16* __restrict__ xq, const float* __restrict__ bcc,
    const float* __restrict__ dtb, const float* __restrict__ acs,
    float* __restrict__ cs)
{
    int h = blockIdx.x, c = blockIdx.y, b = blockIdx.z;
    int t = threadIdx.x;
    int lg = t & 63, pg = t >> 6;     // n0 = 2*lg ; p-range pg*16
    int n0 = lg * 2;
    __shared__ __align__(16) float xdt_s[64 * 68];
    __shared__ float dec_s[64];
    const LL lbase = (LL)b * 4096 + c * 256;
    const int abase = (((b * 16) + c) * 64 + h) * 256;
    float alast = acs[abase + 255];
    float a0[16] = {}, a1[16] = {};
    for (int st = 0; st < 4; ++st) {
        for (int i = 0; i < 16; ++i) {
            int e = t + i * 256; int sp = e >> 6, p = e & 63;
            LL row = lbase + st * 64 + sp;
            xdt_s[sp * 68 + p] = (float)xq[row * 4096 + h * 64 + p] * dtb[(row << 6) + h];
        }
        if (t < 64) dec_s[t] = __expf(alast - acs[abase + st * 64 + t]);
        __syncthreads();
        for (int sp = 0; sp < 64; ++sp) {
            LL row = lbase + st * 64 + sp;
            float2 bb = *(const float2*)&bcc[row * 256 + n0];
            float dd = dec_s[sp];
            float b0 = bb.x * dd, b1 = bb.y * dd;
#pragma unroll
            for (int q = 0; q < 4; ++q) {
                v4f xv = *(const v4f*)&xdt_s[sp * 68 + pg * 16 + q * 4];
#pragma unroll
                for (int j = 0; j < 4; ++j) { a0[q * 4 + j] += b0 * xv[j]; a1[q * 4 + j] += b1 * xv[j]; }
            }
        }
        __syncthreads();
    }
    const LL obase = ((LL)(((b * 16) + c) * 64 + h)) * 8192;
    for (int pp = 0; pp < 16; ++pp) {
        int p = pg * 16 + pp;
        cs[obase + p * 128 + n0]     = a0[pp];
        cs[obase + p * 128 + n0 + 1] = a1[pp];
    }
}

// ---------------- sequential scan over 16 chunks (IN PLACE: cs -> prev) ------
__global__ __launch_bounds__(256) void scan_kernel(
    float* __restrict__ cs, const float* __restrict__ cdec)
{
    int h = blockIdx.x, b = blockIdx.y;
    int t = threadIdx.x;
    float st[32];
#pragma unroll
    for (int i = 0; i < 32; ++i) st[i] = 0.f;
    for (int c = 0; c < 16; ++c) {
        LL base = ((LL)(((b * 16) + c) * 64 + h)) * 8192;
        float cd = cdec[(b * 64 + h) * 16 + c];
#pragma unroll
        for (int i = 0; i < 32; ++i) {
            int e = i * 256 + t;
            float v = cs[base + e];
            cs[base + e] = st[i];
            st[i] = st[i] * cd + v;
        }
    }
}

// ---------------- CBT[b,c,s,l] = sum_n B[s,n]*C[l,n]  ------------------------
__global__ __launch_bounds__(256) void cb_kernel(const float* __restrict__ bcc,
                                                 float* __restrict__ cbt)
{
    int st = blockIdx.x, c = blockIdx.y, b = blockIdx.z;
    int t = threadIdx.x;
    int lg = t & 63, pg = t >> 6;            // rows l = lg+64r ; s' range pg*16
    __shared__ float cr_s[256 * 33];
    __shared__ __align__(16) float brT[32 * 68];
    const LL lbase = (LL)b * 4096 + c * 256;
    float acc[4][16] = {};
    for (int nt = 0; nt < 4; ++nt) {         // n tiles of 32
        for (int i = 0; i < 32; ++i) {
            int e = t + i * 256; int l = e >> 5, np = e & 31;
            cr_s[l * 33 + np] = bcc[(lbase + l) * 256 + 128 + nt * 32 + np];
        }
        for (int i = 0; i < 8; ++i) {
            int e = t + i * 256; int sp = e >> 5, np = e & 31;
            brT[np * 68 + sp] = bcc[(lbase + st * 64 + sp) * 256 + nt * 32 + np];
        }
        __syncthreads();
        for (int np = 0; np < 32; ++np) {
            float w0 = cr_s[lg * 33 + np],         w1 = cr_s[(lg + 64) * 33 + np];
            float w2 = cr_s[(lg + 128) * 33 + np], w3 = cr_s[(lg + 192) * 33 + np];
#pragma unroll
            for (int q = 0; q < 4; ++q) {
                v4f bv = *(const v4f*)&brT[np * 68 + pg * 16 + q * 4];
#pragma unroll
                for (int j = 0; j < 4; ++j) {
                    acc[0][q * 4 + j] += w0 * bv[j]; acc[1][q * 4 + j] += w1 * bv[j];
                    acc[2][q * 4 + j] += w2 * bv[j]; acc[3][q * 4 + j] += w3 * bv[j];
                }
            }
        }
        __syncthreads();
    }
    const LL obase = ((LL)((b * 16) + c)) * 65536;
#pragma unroll
    for (int r = 0; r < 4; ++r)
        for (int sp = 0; sp < 16; ++sp) {
            int s = st * 64 + pg * 16 + sp;
            cbt[obase + (LL)s * 256 + (lg + r * 64)] = acc[r][sp];
        }
}

// ---------------- SSD output: Y = Yd + Yo + D*x, written OVER x in xq --------
__global__ __launch_bounds__(256) void ssd_y_kernel(
    __bf16* __restrict__ xq, const float* __restrict__ bcc,
    const float* __restrict__ dtb, const float* __restrict__ acs,
    const float* __restrict__ cbt, const float* __restrict__ prevS,
    const float* __restrict__ Dv)
{
    int h = blockIdx.x, c = blockIdx.y, b = blockIdx.z;
    int t = threadIdx.x;
    int lg = t & 63, pg = t >> 6;            // rows l = lg+64r ; p range pg*16
    const int p0 = pg * 16;
    __shared__ float acs_s[256];
    __shared__ __align__(16) float prevT[128][68];   // prevT[n][p]
    __shared__ __align__(16) float shx[256 * 17];    // union: C tile / xdt tile
    const LL lbase = (LL)b * 4096 + c * 256;
    const int abase = (((b * 16) + c) * 64 + h) * 256;
    acs_s[t] = acs[abase + t];
    const LL pbase = ((LL)(((b * 16) + c) * 64 + h)) * 8192;
    for (int i = 0; i < 32; ++i) {
        int e = t + i * 256; int p = e >> 7, n = e & 127;
        prevT[n][p] = prevS[pbase + e];
    }
    __syncthreads();
    float accv[4][16] = {};
    int lr[4]; float acl[4], ea[4];
#pragma unroll
    for (int r = 0; r < 4; ++r) { lr[r] = lg + r * 64; acl[r] = acs_s[lr[r]]; ea[r] = __expf(acl[r]); }

    // ---- Yo: sum_n C[l,n]*prevT[n,p] (scaled by ea after), n tiles of 16
    for (int nt = 0; nt < 8; ++nt) {
        for (int i = 0; i < 16; ++i) {
            int e = t + i * 256; int l = e >> 4, np = e & 15;
            shx[l * 17 + np] = bcc[(lbase + l) * 256 + 128 + nt * 16 + np];
        }
        __syncthreads();
        for (int np = 0; np < 16; ++np) {
            int n = nt * 16 + np;
            float w0 = shx[lr[0] * 17 + np], w1 = shx[lr[1] * 17 + np];
            float w2 = shx[lr[2] * 17 + np], w3 = shx[lr[3] * 17 + np];
#pragma unroll
            for (int q = 0; q < 4; ++q) {
                v4f pv = *(const v4f*)&prevT[n][p0 + q * 4];
#pragma unroll
                for (int j = 0; j < 4; ++j) {
                    accv[0][q * 4 + j] += w0 * pv[j]; accv[1][q * 4 + j] += w1 * pv[j];
                    accv[2][q * 4 + j] += w2 * pv[j]; accv[3][q * 4 + j] += w3 * pv[j];
                }
            }
        }
        __syncthreads();
    }
    // scale by exp(Acs_l) and add D*x
    float Dh = Dv[h];
#pragma unroll
    for (int r = 0; r < 4; ++r) {
        LL xb = (lbase + lr[r]) * 4096 + h * 64 + p0;
        float e = ea[r];
        for (int pp = 0; pp < 16; ++pp)
            accv[r][pp] = accv[r][pp] * e + Dh * (float)xq[xb + pp];
    }
    // ---- Yd: sum_{s<=l} CB[l,s]*exp(acl-acs[s])*xdt[s,p], s tiles of 64
    const LL cbbase = ((LL)((b * 16) + c)) * 65536;
    for (int st = 0; st < 4; ++st) {
        for (int i = 0; i < 16; ++i) {
            int e = t + i * 256; int sp = e >> 6, p = e & 63;
            LL row = lbase + st * 64 + sp;
            shx[sp * 68 + p] = (float)xq[row * 4096 + h * 64 + p] * dtb[(row << 6) + h];
        }
        __syncthreads();
        for (int sp = 0; sp < 64; ++sp) {
            int s = st * 64 + sp;
            float as = acs_s[s];
            float w[4];
#pragma unroll
            for (int r = 0; r < 4; ++r) {
                float cbv = cbt[cbbase + (LL)s * 256 + lr[r]];
                float d = acl[r] - as;
                w[r] = (s <= lr[r]) ? cbv * __expf(d) : 0.f;   // select kills inf path
            }
#pragma unroll
            for (int q = 0; q < 4; ++q) {
                v4f xv = *(const v4f*)&shx[sp * 68 + p0 + q * 4];
#pragma unroll
                for (int j = 0; j < 4; ++j) {
                    accv[0][q * 4 + j] += w[0] * xv[j]; accv[1][q * 4 + j] += w[1] * xv[j];
                    accv[2][q * 4 + j] += w[2] * xv[j]; accv[3][q * 4 + j] += w[3] * xv[j];
                }
            }
        }
        __syncthreads();
    }
    // write Y over x region (this block is the only reader of these cells)
#pragma unroll
    for (int r = 0; r < 4; ++r) {
        LL ob = (lbase + lr[r]) * 4096 + h * 64 + p0;
        for (int pp = 0; pp < 16; ++pp) xq[ob + pp] = (__bf16)accv[r][pp];
    }
}

// ---------------- gated RMSNorm (in-place on xq, stride 4096) ----------------
__global__ __launch_bounds__(256) void rmsnorm_kernel(
    __bf16* __restrict__ y, const __bf16* __restrict__ z,
    const float* __restrict__ nw)
{
    LL r = blockIdx.x;
    int t = threadIdx.x;
    float vals[16]; float ss = 0.f;
#pragma unroll
    for (int i = 0; i < 16; ++i) {
        int j = i * 256 + t;
        float yv = (float)y[r * 4096 + j];
        float zv = (float)z[r * 4096 + j];
        float v = yv * (zv / (1.f + __expf(-zv)));
        vals[i] = v; ss += v * v;
    }
#pragma unroll
    for (int off = 32; off >= 1; off >>= 1) ss += __shfl_down(ss, off, 64);
    __shared__ float red[4];
    if ((t & 63) == 0) red[t >> 6] = ss;
    __syncthreads();
    float tot = red[0] + red[1] + red[2] + red[3];
    float rstd = rsqrtf(tot * (1.f / 4096.f) + 1e-5f);
#pragma unroll
    for (int i = 0; i < 16; ++i) {
        int j = i * 256 + t;
        y[r * 4096 + j] = (__bf16)(vals[i] * rstd * nw[j]);
    }
}

// ---------------------------------------------------------------------------
extern "C" void kernel_launch(void* const* d_in, const int* in_sizes, int n_in,
                              void* d_out, int out_size, void* d_ws, size_t ws_size,
                              hipStream_t stream) {
    const float* hs    = (const float*)d_in[0];   // (2,4096,2048)
    const float* w1    = (const float*)d_in[1];   // (8512,2048)
    const float* cw    = (const float*)d_in[2];   // (4352,4)
    const float* cbias = (const float*)d_in[3];   // (4352,)
    const float* dtbi  = (const float*)d_in[4];   // (64,)
    const float* alog  = (const float*)d_in[5];   // (64,)
    const float* Dv    = (const float*)d_in[6];   // (64,)
    const float* nw    = (const float*)d_in[7];   // (4096,)
    const float* wo    = (const float*)d_in[8];   // (2048,4096)
    float* out = (float*)d_out;
    (void)in_sizes; (void)n_in; (void)out_size; (void)ws_size;

    char* ws = (char*)d_ws;
    size_t off = 0;
    auto alloc = [&](size_t bytes) { void* p = ws + off; off += (bytes + 255) & ~(size_t)255; return p; };
    __bf16* xp_b  = (__bf16*)alloc((size_t)8192 * 4096 * 2);        // 67.1 MB
    __bf16* xq_b  = (__bf16*)alloc((size_t)8192 * 4096 * 2);        // 67.1 MB
    float*  bcr_f = (float*) alloc((size_t)8192 * 256 * 4);         // 8.4 MB
    float*  bcc_f = (float*) alloc((size_t)8192 * 256 * 4);         // 8.4 MB
    float*  dt_f  = (float*) alloc((size_t)8192 * 64 * 4);          // 2.1 MB
    float*  acs_f = (float*) alloc((size_t)2 * 16 * 64 * 256 * 4);  // 2.1 MB
    float*  cd_f  = (float*) alloc((size_t)2 * 64 * 16 * 4);        // 8 KB
    float*  cbt_f = (float*) alloc((size_t)2 * 16 * 256 * 256 * 4); // 8.4 MB
    float*  cs_f  = (float*)xp_b;           // aliases xp_b AFTER conv_x
    __bf16* z_b   = (__bf16*)d_out;         // z lives in d_out until GEMM2

    // 1. in-projection GEMM (bf16 MFMA), cols 0..8192: z / x
    gemm_bt<float, float, 1><<<dim3(64, 64), 256, 0, stream>>>(
        hs, w1, 2048, 2048, 2048, z_b, xp_b, nullptr, 0);
    // 1b. B/C/dt columns in fp32 (feed CB matmul + exp(cumsum) — bf16 too lossy)
    f32_gemm_kernel<<<dim3(128, 5), 256, 0, stream>>>(hs, w1, dtbi, bcr_f, dt_f);
    // 2. causal conv + SiLU
    conv_x_kernel<<<dim3(16, 4096, 2), 256, 0, stream>>>(xp_b, cw, cbias, xq_b);
    conv_bc_kernel<<<dim3(1, 4096, 2), 256, 0, stream>>>(bcr_f, cw, cbias, bcc_f);
    // 3. per-chunk cumsum of dA
    cumsum_kernel<<<dim3(64, 16, 2), 256, 0, stream>>>(dt_f, alog, acs_f, cd_f);
    // 4. chunk states (writes over dead xp_b region)
    chunk_state_kernel<<<dim3(64, 16, 2), 256, 0, stream>>>(xq_b, bcc_f, dt_f, acs_f, cs_f);
    // 5. inter-chunk scan (in place: cs -> prev-state)
    scan_kernel<<<dim3(64, 2), 256, 0, stream>>>(cs_f, cd_f);
    // 6. CB^T (fp32, shared across heads)
    cb_kernel<<<dim3(4, 16, 2), 256, 0, stream>>>(bcc_f, cbt_f);
    // 7. SSD output Y (bf16), written over x region of xq
    ssd_y_kernel<<<dim3(64, 16, 2), 256, 0, stream>>>(xq_b, bcc_f, dt_f, acs_f, cbt_f, cs_f, Dv);
    // 8. gated RMSNorm (in place on xq)
    rmsnorm_kernel<<<8192, 256, 0, stream>>>(xq_b, z_b, nw);
    // 9. out-projection GEMM -> d_out fp32
    gemm_bt<__bf16, float, 2><<<dim3(16, 64), 256, 0, stream>>>(
        xq_b, wo, 4096, 4096, 4096, nullptr, nullptr, out, 2048);
}

// Round 5
// 2036.141 us; speedup vs baseline: 1.2932x; 1.2932x over previous
//
#include <hip/hip_runtime.h>
#include <hip/hip_bf16.h>

// ---------------------------------------------------------------------------
// Mamba2 mixer forward on MI355X (gfx950).
// HID=2048 DSTATE=128 K=4 DIN=4096 HDIM=64 NH=64 CHUNK=256, B=2 L=4096
//
// Precision plan (absmax budget 0.108, ref fp32):
//   - B, C, dt fp32 end-to-end up to CB/cumsum/scan (amplifying sums).
//   - ssd_y: W=CB*Lmat and C*exp(Acs) rounded to bf16 AFTER fp32 sums, then
//     bf16 MFMA (one rounding, not amplified). x path bf16 throughout.
//
// Workspace (~166 MiB): xp(67)+xq(67)+bcr(8.4)+bcc(8.4)+dt(2.1)+acs(2.1)
//                       +cd+cbt(8.4); cs/prev alias xp after conv.
// z (bf16 [8192,4096]) lives in d_out until GEMM2 rewrites it.
// ---------------------------------------------------------------------------

typedef __bf16 v8bf __attribute__((ext_vector_type(8)));
typedef float  v4f  __attribute__((ext_vector_type(4)));

#define LL long long

__device__ inline v8bf load8(const __bf16* p) { return *(const v8bf*)p; }
__device__ inline v8bf load8(const float* p) {
    v4f a = *(const v4f*)p, b = *(const v4f*)(p + 4);
    v8bf r;
#pragma unroll
    for (int i = 0; i < 4; ++i) { r[i] = (__bf16)a[i]; r[i + 4] = (__bf16)b[i]; }
    return r;
}

// ---------------- bf16 MFMA GEMM:  C[M,N] = A[M,K] * B[N,K]^T ----------------
template <typename TA, typename TB, int MODE>
__global__ __launch_bounds__(256) void gemm_bt(
    const TA* __restrict__ A, const TB* __restrict__ B, int K, int lda, int ldb,
    __bf16* __restrict__ z_out, __bf16* __restrict__ x_out,
    float* __restrict__ outf, int ldc)
{
    __shared__ __align__(16) __bf16 As[128][40];
    __shared__ __align__(16) __bf16 Bs[128][40];
    const int tid  = threadIdx.x;
    const int lane = tid & 63;
    const int wave = tid >> 6;
    const int wm = (wave & 1) * 64, wn = (wave >> 1) * 64;
    const int m0 = blockIdx.y * 128, n0 = blockIdx.x * 128;
    const int lrow = lane & 15, quad = lane >> 4;
    v4f acc[4][4] = {};

    for (int k0 = 0; k0 < K; k0 += 32) {
#pragma unroll
        for (int i = 0; i < 2; ++i) {
            int e = tid + i * 256;            // 0..511
            int row = e >> 2, c8 = (e & 3) << 3;
            *(v8bf*)&As[row][c8] = load8(&A[(LL)(m0 + row) * lda + k0 + c8]);
            *(v8bf*)&Bs[row][c8] = load8(&B[(LL)(n0 + row) * ldb + k0 + c8]);
        }
        __syncthreads();
        v8bf af[4], bfr[4];
#pragma unroll
        for (int i = 0; i < 4; ++i) af[i]  = *(const v8bf*)&As[wm + i * 16 + lrow][quad * 8];
#pragma unroll
        for (int j = 0; j < 4; ++j) bfr[j] = *(const v8bf*)&Bs[wn + j * 16 + lrow][quad * 8];
#pragma unroll
        for (int i = 0; i < 4; ++i)
#pragma unroll
            for (int j = 0; j < 4; ++j)
                acc[i][j] = __builtin_amdgcn_mfma_f32_16x16x32_bf16(af[i], bfr[j], acc[i][j], 0, 0, 0);
        __syncthreads();
    }
#pragma unroll
    for (int i = 0; i < 4; ++i)
#pragma unroll
        for (int j = 0; j < 4; ++j)
#pragma unroll
            for (int r = 0; r < 4; ++r) {
                int row = m0 + wm + i * 16 + quad * 4 + r;
                int col = n0 + wn + j * 16 + lrow;
                float v = acc[i][j][r];
                if constexpr (MODE == 1) {
                    if (col < 4096) z_out[(LL)row * 4096 + col] = (__bf16)v;
                    else            x_out[(LL)row * 4096 + (col - 4096)] = (__bf16)v;
                } else {
                    outf[(LL)row * ldc + col] = v;
                }
            }
}

// ---------------- fp32 GEMM for B/C/dt columns (zxbcdt cols 8192..8512) ------
__global__ __launch_bounds__(256) void f32_gemm_kernel(
    const float* __restrict__ hs, const float* __restrict__ w1,
    const float* __restrict__ dtbi, float* __restrict__ bcr,
    float* __restrict__ dt)
{
    const int row0 = blockIdx.x * 64;
    const int cg = blockIdx.y;               // 0..4
    const int wrow0 = 8192 + cg * 64;
    const int t = threadIdx.x;
    const int col = t & 63, rg = t >> 6;
    __shared__ __align__(16) float As[64][68];
    __shared__ __align__(16) float Ws[64][68];
    float acc[16] = {};
    for (int k0 = 0; k0 < 2048; k0 += 64) {
#pragma unroll
        for (int i = 0; i < 16; ++i) {
            int e = t + i * 256; int kk = e & 63, row = e >> 6;
            As[kk][row] = hs[(LL)(row0 + row) * 2048 + k0 + kk];
            Ws[kk][row] = w1[(LL)(wrow0 + row) * 2048 + k0 + kk];
        }
        __syncthreads();
        for (int kk = 0; kk < 64; ++kk) {
            float w = Ws[kk][col];
#pragma unroll
            for (int q = 0; q < 4; ++q) {
                v4f a = *(const v4f*)&As[kk][rg * 16 + q * 4];
#pragma unroll
                for (int j = 0; j < 4; ++j) acc[q * 4 + j] += a[j] * w;
            }
        }
        __syncthreads();
    }
    if (cg < 4) {
#pragma unroll
        for (int i = 0; i < 16; ++i) {
            int row = row0 + rg * 16 + i;
            bcr[(LL)row * 256 + cg * 64 + col] = acc[i];
        }
    } else {
        float bias = dtbi[col];
#pragma unroll
        for (int i = 0; i < 16; ++i) {
            int row = row0 + rg * 16 + i;
            float x = acc[i] + bias;
            dt[row * 64 + col] = (x > 20.f) ? x : log1pf(__expf(x));
        }
    }
}

// ---------------- causal conv1d (K=4) + SiLU, x channels (bf16) --------------
__global__ __launch_bounds__(256) void conv_x_kernel(
    const __bf16* __restrict__ xp, const float* __restrict__ cw,
    const float* __restrict__ cbias, __bf16* __restrict__ xq)
{
    int ch = blockIdx.x * 256 + threadIdx.x;
    int l = blockIdx.y, b = blockIdx.z;
    float acc = cbias[ch];
#pragma unroll
    for (int i = 0; i < 4; ++i) {
        int ls = l - 3 + i;
        if (ls >= 0)
            acc += (float)xp[((LL)b * 4096 + ls) * 4096 + ch] * cw[ch * 4 + i];
    }
    acc = acc / (1.f + __expf(-acc));
    xq[((LL)b * 4096 + l) * 4096 + ch] = (__bf16)acc;
}

// ---------------- causal conv1d (K=4) + SiLU, B/C channels (fp32) ------------
__global__ __launch_bounds__(256) void conv_bc_kernel(
    const float* __restrict__ bcr, const float* __restrict__ cw,
    const float* __restrict__ cbias, float* __restrict__ bcc)
{
    int ch = threadIdx.x;
    int l = blockIdx.y, b = blockIdx.z;
    float acc = cbias[4096 + ch];
#pragma unroll
    for (int i = 0; i < 4; ++i) {
        int ls = l - 3 + i;
        if (ls >= 0)
            acc += bcr[((LL)b * 4096 + ls) * 256 + ch] * cw[(4096 + ch) * 4 + i];
    }
    acc = acc / (1.f + __expf(-acc));
    bcc[((LL)b * 4096 + l) * 256 + ch] = acc;
}

// ---------------- per-chunk inclusive cumsum of dA = dt*A --------------------
__global__ __launch_bounds__(256) void cumsum_kernel(
    const float* __restrict__ dt, const float* __restrict__ alog,
    float* __restrict__ acs, float* __restrict__ cdec)
{
    int h = blockIdx.x, c = blockIdx.y, b = blockIdx.z;
    int s = threadIdx.x;
    __shared__ float buf[256];
    float Av = -expf(alog[h]);
    int bl = b * 4096 + c * 256 + s;
    buf[s] = dt[bl * 64 + h] * Av;
    __syncthreads();
    for (int off = 1; off < 256; off <<= 1) {
        float v = (s >= off) ? buf[s - off] : 0.f;
        __syncthreads();
        buf[s] += v;
        __syncthreads();
    }
    int abase = (((b * 16) + c) * 64 + h) * 256;
    acs[abase + s] = buf[s];
    if (s == 255) cdec[(b * 64 + h) * 16 + c] = expf(buf[s]);
}

// ---------------- chunk states: cs[b,c,h,p,n] = sum_s B[s,n]*dec[s]*x[s,p]*dt[s]
__global__ __launch_bounds__(256) void chunk_state_kernel(
    const __bf16* __restrict__ xq, const float* __restrict__ bcc,
    const float* __restrict__ dtb, const float* __restrict__ acs,
    float* __restrict__ cs)
{
    int h = blockIdx.x, c = blockIdx.y, b = blockIdx.z;
    int t = threadIdx.x;
    int lg = t & 63, pg = t >> 6;
    int n0 = lg * 2;
    __shared__ __align__(16) float xdt_s[64 * 68];
    __shared__ float dec_s[64];
    const LL lbase = (LL)b * 4096 + c * 256;
    const int abase = (((b * 16) + c) * 64 + h) * 256;
    float alast = acs[abase + 255];
    float a0[16] = {}, a1[16] = {};
    for (int st = 0; st < 4; ++st) {
        for (int i = 0; i < 16; ++i) {
            int e = t + i * 256; int sp = e >> 6, p = e & 63;
            LL row = lbase + st * 64 + sp;
            xdt_s[sp * 68 + p] = (float)xq[row * 4096 + h * 64 + p] * dtb[(row << 6) + h];
        }
        if (t < 64) dec_s[t] = __expf(alast - acs[abase + st * 64 + t]);
        __syncthreads();
        for (int sp = 0; sp < 64; ++sp) {
            LL row = lbase + st * 64 + sp;
            float2 bb = *(const float2*)&bcc[row * 256 + n0];
            float dd = dec_s[sp];
            float b0 = bb.x * dd, b1 = bb.y * dd;
#pragma unroll
            for (int q = 0; q < 4; ++q) {
                v4f xv = *(const v4f*)&xdt_s[sp * 68 + pg * 16 + q * 4];
#pragma unroll
                for (int j = 0; j < 4; ++j) { a0[q * 4 + j] += b0 * xv[j]; a1[q * 4 + j] += b1 * xv[j]; }
            }
        }
        __syncthreads();
    }
    const LL obase = ((LL)(((b * 16) + c) * 64 + h)) * 8192;
    for (int pp = 0; pp < 16; ++pp) {
        int p = pg * 16 + pp;
        cs[obase + p * 128 + n0]     = a0[pp];
        cs[obase + p * 128 + n0 + 1] = a1[pp];
    }
}

// ---------------- sequential scan over 16 chunks (IN PLACE: cs -> prev) ------
__global__ __launch_bounds__(256) void scan_kernel(
    float* __restrict__ cs, const float* __restrict__ cdec)
{
    int h = blockIdx.x, b = blockIdx.y;
    int t = threadIdx.x;
    float st[32];
#pragma unroll
    for (int i = 0; i < 32; ++i) st[i] = 0.f;
    for (int c = 0; c < 16; ++c) {
        LL base = ((LL)(((b * 16) + c) * 64 + h)) * 8192;
        float cd = cdec[(b * 64 + h) * 16 + c];
#pragma unroll
        for (int i = 0; i < 32; ++i) {
            int e = i * 256 + t;
            float v = cs[base + e];
            cs[base + e] = st[i];
            st[i] = st[i] * cd + v;
        }
    }
}

// ---------------- CBT[b,c,s,l] = sum_n B[s,n]*C[l,n]  ------------------------
__global__ __launch_bounds__(256) void cb_kernel(const float* __restrict__ bcc,
                                                 float* __restrict__ cbt)
{
    int st = blockIdx.x, c = blockIdx.y, b = blockIdx.z;
    int t = threadIdx.x;
    int lg = t & 63, pg = t >> 6;
    __shared__ float cr_s[256 * 33];
    __shared__ __align__(16) float brT[32 * 68];
    const LL lbase = (LL)b * 4096 + c * 256;
    float acc[4][16] = {};
    for (int nt = 0; nt < 4; ++nt) {
        for (int i = 0; i < 32; ++i) {
            int e = t + i * 256; int l = e >> 5, np = e & 31;
            cr_s[l * 33 + np] = bcc[(lbase + l) * 256 + 128 + nt * 32 + np];
        }
        for (int i = 0; i < 8; ++i) {
            int e = t + i * 256; int sp = e >> 5, np = e & 31;
            brT[np * 68 + sp] = bcc[(lbase + st * 64 + sp) * 256 + nt * 32 + np];
        }
        __syncthreads();
        for (int np = 0; np < 32; ++np) {
            float w0 = cr_s[lg * 33 + np],         w1 = cr_s[(lg + 64) * 33 + np];
            float w2 = cr_s[(lg + 128) * 33 + np], w3 = cr_s[(lg + 192) * 33 + np];
#pragma unroll
            for (int q = 0; q < 4; ++q) {
                v4f bv = *(const v4f*)&brT[np * 68 + pg * 16 + q * 4];
#pragma unroll
                for (int j = 0; j < 4; ++j) {
                    acc[0][q * 4 + j] += w0 * bv[j]; acc[1][q * 4 + j] += w1 * bv[j];
                    acc[2][q * 4 + j] += w2 * bv[j]; acc[3][q * 4 + j] += w3 * bv[j];
                }
            }
        }
        __syncthreads();
    }
    const LL obase = ((LL)((b * 16) + c)) * 65536;
#pragma unroll
    for (int r = 0; r < 4; ++r)
        for (int sp = 0; sp < 16; ++sp) {
            int s = st * 64 + pg * 16 + sp;
            cbt[obase + (LL)s * 256 + (lg + r * 64)] = acc[r][sp];
        }
}

// ---------------- SSD output via MFMA: Y[256,64] = A[256,384]·Bm[384,64] -----
// A = [W | C*exp(Acs_l)] (built fp32 -> bf16), Bm = [xdt ; prev].
// K-blocks of 64: kb 0..3 = Yd s-blocks, kb 4..5 = Yo n-blocks.
// B tile is XOR-swizzled: (kk,p) stored at Bs[p*64 + ((kk>>3 ^ (p&7))<<3 | kk&7)]
// so transposed b16 writes AND b128 frag reads are both <=2-way (free, m136).
// Epilogue: acc + D*x, written OVER x region of xq (owner-lane only: safe).
__global__ __launch_bounds__(256) void ssd_y_kernel(
    __bf16* __restrict__ xq, const float* __restrict__ bcc,
    const float* __restrict__ dtb, const float* __restrict__ acs,
    const float* __restrict__ cbt, const float* __restrict__ prevS,
    const float* __restrict__ Dv)
{
    const int h = blockIdx.x, c = blockIdx.y, b = blockIdx.z;
    const int t = threadIdx.x;
    const int lane = t & 63, wave = t >> 6;
    const int lrow = lane & 15, quad = lane >> 4;
    const int wm = wave * 64;
    __shared__ __align__(16) __bf16 As[256][72];     // rows l, 64 k (+8 pad)
    __shared__ __align__(16) __bf16 Bs[64 * 64];     // swizzled [p][k]
    __shared__ float acs_s[256];
    const LL lbase = (LL)b * 4096 + c * 256;
    const int abase = (((b * 16) + c) * 64 + h) * 256;
    acs_s[t] = acs[abase + t];
    __syncthreads();
    const float acl_t = acs_s[t];                    // builder row l = t
    const float ea_t  = __expf(acl_t);
    const LL cbbase = ((LL)((b * 16) + c)) * 65536;
    const LL pbase  = ((LL)(((b * 16) + c) * 64 + h)) * 8192;
    v4f acc[4][4] = {};

    for (int kb = 0; kb < 6; ++kb) {
        // ---- build A tile (thread t owns row l = t; 8 groups of 8 k)
        if (kb < 4) {
            const int sb = kb * 64;
#pragma unroll
            for (int g = 0; g < 8; ++g) {
                v8bf wv;
#pragma unroll
                for (int u = 0; u < 8; ++u) {
                    int s = sb + g * 8 + u;
                    float cbv = cbt[cbbase + (LL)s * 256 + t];
                    float d = acl_t - acs_s[s];
                    wv[u] = (__bf16)((s <= t) ? cbv * __expf(d) : 0.f);
                }
                *(v8bf*)&As[t][g * 8] = wv;
            }
        } else {
            const int nb = (kb - 4) * 64;
            const LL cb0 = (lbase + t) * 256 + 128 + nb;
#pragma unroll
            for (int g = 0; g < 8; ++g) {
                v4f c0 = *(const v4f*)&bcc[cb0 + g * 8];
                v4f c1 = *(const v4f*)&bcc[cb0 + g * 8 + 4];
                v8bf wv;
#pragma unroll
                for (int u = 0; u < 4; ++u) {
                    wv[u]     = (__bf16)(c0[u] * ea_t);
                    wv[u + 4] = (__bf16)(c1[u] * ea_t);
                }
                *(v8bf*)&As[t][g * 8] = wv;
            }
        }
        // ---- build B tile [p][kk], swizzled
        if (kb < 4) {
            const int sb = kb * 64;
#pragma unroll
            for (int i = 0; i < 16; ++i) {
                int e = t + i * 256; int p = e & 63, sp = e >> 6;
                LL row = lbase + sb + sp;
                float xv = (float)xq[row * 4096 + h * 64 + p] * dtb[((int)(row)) * 64 + h];
                Bs[p * 64 + ((((sp >> 3) ^ (p & 7)) << 3) | (sp & 7))] = (__bf16)xv;
            }
        } else {
            const int nb = (kb - 4) * 64;
#pragma unroll
            for (int i = 0; i < 16; ++i) {
                int e = t + i * 256; int n = e & 63, p = e >> 6;
                float pv = prevS[pbase + (LL)p * 128 + nb + n];
                Bs[p * 64 + ((((n >> 3) ^ (p & 7)) << 3) | (n & 7))] = (__bf16)pv;
            }
        }
        __syncthreads();
        // ---- MFMA: 2 ksteps of 32
#pragma unroll
        for (int ks = 0; ks < 2; ++ks) {
            v8bf af[4], bfv[4];
#pragma unroll
            for (int i = 0; i < 4; ++i)
                af[i] = *(const v8bf*)&As[wm + i * 16 + lrow][ks * 32 + quad * 8];
#pragma unroll
            for (int j = 0; j < 4; ++j) {
                int p = j * 16 + lrow;
                int kg = (ks * 4 + quad) ^ (p & 7);
                bfv[j] = *(const v8bf*)&Bs[p * 64 + kg * 8];
            }
#pragma unroll
            for (int i = 0; i < 4; ++i)
#pragma unroll
                for (int j = 0; j < 4; ++j)
                    acc[i][j] = __builtin_amdgcn_mfma_f32_16x16x32_bf16(af[i], bfv[j], acc[i][j], 0, 0, 0);
        }
        __syncthreads();
    }
    // ---- epilogue: + D*x, write Y over x region (owner lane reads own cell)
    const float Dh = Dv[h];
#pragma unroll
    for (int i = 0; i < 4; ++i)
#pragma unroll
        for (int j = 0; j < 4; ++j)
#pragma unroll
            for (int r = 0; r < 4; ++r) {
                int l = wm + i * 16 + quad * 4 + r;
                int p = j * 16 + lrow;
                LL idx = (lbase + l) * 4096 + h * 64 + p;
                float v = acc[i][j][r] + Dh * (float)xq[idx];
                xq[idx] = (__bf16)v;
            }
}

// ---------------- gated RMSNorm (in-place on xq, stride 4096) ----------------
__global__ __launch_bounds__(256) void rmsnorm_kernel(
    __bf16* __restrict__ y, const __bf16* __restrict__ z,
    const float* __restrict__ nw)
{
    LL r = blockIdx.x;
    int t = threadIdx.x;
    float vals[16]; float ss = 0.f;
#pragma unroll
    for (int i = 0; i < 16; ++i) {
        int j = i * 256 + t;
        float yv = (float)y[r * 4096 + j];
        float zv = (float)z[r * 4096 + j];
        float v = yv * (zv / (1.f + __expf(-zv)));
        vals[i] = v; ss += v * v;
    }
#pragma unroll
    for (int off = 32; off >= 1; off >>= 1) ss += __shfl_down(ss, off, 64);
    __shared__ float red[4];
    if ((t & 63) == 0) red[t >> 6] = ss;
    __syncthreads();
    float tot = red[0] + red[1] + red[2] + red[3];
    float rstd = rsqrtf(tot * (1.f / 4096.f) + 1e-5f);
#pragma unroll
    for (int i = 0; i < 16; ++i) {
        int j = i * 256 + t;
        y[r * 4096 + j] = (__bf16)(vals[i] * rstd * nw[j]);
    }
}

// ---------------------------------------------------------------------------
extern "C" void kernel_launch(void* const* d_in, const int* in_sizes, int n_in,
                              void* d_out, int out_size, void* d_ws, size_t ws_size,
                              hipStream_t stream) {
    const float* hs    = (const float*)d_in[0];
    const float* w1    = (const float*)d_in[1];
    const float* cw    = (const float*)d_in[2];
    const float* cbias = (const float*)d_in[3];
    const float* dtbi  = (const float*)d_in[4];
    const float* alog  = (const float*)d_in[5];
    const float* Dv    = (const float*)d_in[6];
    const float* nw    = (const float*)d_in[7];
    const float* wo    = (const float*)d_in[8];
    float* out = (float*)d_out;
    (void)in_sizes; (void)n_in; (void)out_size; (void)ws_size;

    char* ws = (char*)d_ws;
    size_t off = 0;
    auto alloc = [&](size_t bytes) { void* p = ws + off; off += (bytes + 255) & ~(size_t)255; return p; };
    __bf16* xp_b  = (__bf16*)alloc((size_t)8192 * 4096 * 2);
    __bf16* xq_b  = (__bf16*)alloc((size_t)8192 * 4096 * 2);
    float*  bcr_f = (float*) alloc((size_t)8192 * 256 * 4);
    float*  bcc_f = (float*) alloc((size_t)8192 * 256 * 4);
    float*  dt_f  = (float*) alloc((size_t)8192 * 64 * 4);
    float*  acs_f = (float*) alloc((size_t)2 * 16 * 64 * 256 * 4);
    float*  cd_f  = (float*) alloc((size_t)2 * 64 * 16 * 4);
    float*  cbt_f = (float*) alloc((size_t)2 * 16 * 256 * 256 * 4);
    float*  cs_f  = (float*)xp_b;           // aliases xp_b AFTER conv_x
    __bf16* z_b   = (__bf16*)d_out;

    gemm_bt<float, float, 1><<<dim3(64, 64), 256, 0, stream>>>(
        hs, w1, 2048, 2048, 2048, z_b, xp_b, nullptr, 0);
    f32_gemm_kernel<<<dim3(128, 5), 256, 0, stream>>>(hs, w1, dtbi, bcr_f, dt_f);
    conv_x_kernel<<<dim3(16, 4096, 2), 256, 0, stream>>>(xp_b, cw, cbias, xq_b);
    conv_bc_kernel<<<dim3(1, 4096, 2), 256, 0, stream>>>(bcr_f, cw, cbias, bcc_f);
    cumsum_kernel<<<dim3(64, 16, 2), 256, 0, stream>>>(dt_f, alog, acs_f, cd_f);
    chunk_state_kernel<<<dim3(64, 16, 2), 256, 0, stream>>>(xq_b, bcc_f, dt_f, acs_f, cs_f);
    scan_kernel<<<dim3(64, 2), 256, 0, stream>>>(cs_f, cd_f);
    cb_kernel<<<dim3(4, 16, 2), 256, 0, stream>>>(bcc_f, cbt_f);
    ssd_y_kernel<<<dim3(64, 16, 2), 256, 0, stream>>>(xq_b, bcc_f, dt_f, acs_f, cbt_f, cs_f, Dv);
    rmsnorm_kernel<<<8192, 256, 0, stream>>>(xq_b, z_b, nw);
    gemm_bt<__bf16, float, 2><<<dim3(16, 64), 256, 0, stream>>>(
        xq_b, wo, 4096, 4096, 4096, nullptr, nullptr, out, 2048);
}